// Round 14
// baseline (8143.449 us; speedup 1.0000x reference)
//
#include <hip/hip_runtime.h>
#include <hip/hip_bf16.h>
#include <cmath>

// ---------------- types & helpers ----------------
typedef __attribute__((ext_vector_type(8))) short short8;   // 8 bf16
typedef __attribute__((ext_vector_type(4))) float f32x4;
typedef __attribute__((ext_vector_type(2))) float f32x2;
typedef __attribute__((ext_vector_type(4))) unsigned int u32x4;

__device__ inline float bf2f(ushort u) {
    unsigned v = (unsigned)u << 16; float f; __builtin_memcpy(&f, &v, 4); return f;
}
__device__ inline ushort f2bf(float f) {
    __hip_bfloat16 h = __float2bfloat16(f); ushort u; __builtin_memcpy(&u, &h, 2); return u;
}
__device__ inline float sigf(float z) { return 1.f / (1.f + expf(-z)); }

// publish store (agent scope — r13; equivalent to system per measurements)
__device__ __forceinline__ void agst32(void* p, unsigned v) {
    __hip_atomic_store((unsigned*)p, v, __ATOMIC_RELAXED, __HIP_MEMORY_SCOPE_AGENT);
}

// dims
#define BB 256
#define LL 256
#define HH 512
#define G4 2048

// XOR swizzle for 1024-B LDS rows (proven r4-r13)
__device__ __forceinline__ unsigned swz(unsigned row, unsigned byteInRow) {
    return (row * 1024u + byteInRow) ^ ((row & 7u) << 4);
}

// ---- r14 sync machinery -----------------------------------------------------
// Sub-flags: flags[rb*64 + cs*4 + wave]. Producer: each wave drains its own
// publish stores then lane0 stores its sub-flag (NO workgroup barrier).
__device__ __forceinline__ void arrive_wave(unsigned* fl, int cs, unsigned epoch, int tid) {
    asm volatile("s_waitcnt vmcnt(0)" ::: "memory");   // this wave's stores done
    if ((tid & 63) == 0)
        __hip_atomic_store(fl + cs * 4 + (tid >> 6), epoch,
                           __ATOMIC_RELAXED, __HIP_MEMORY_SCOPE_AGENT);
}

// Fused poll+stage: wave w stages col-chunks 4w..4w+3 (lane l: row = l&15,
// producer p = 4w + (l>>4)). Each lane divergently polls one (p, sub) flag
// covering all 16 sub-flags of the wave's 4 producers, then loads its 64B
// and ds_writes swizzled. Early producers' data loads overlap late polls.
__device__ __forceinline__ void stage_poll(
    const ushort* __restrict__ Ag, int r0, ushort* Ast,
    unsigned* __restrict__ fl, unsigned epoch, int tid)
{
    int w = tid >> 6, l = tid & 63;
    int p = 4 * w + (l >> 4);
    int row = l & 15;
    unsigned* myf = fl + p * 4 + (l & 3);
    while (__hip_atomic_load(myf, __ATOMIC_RELAXED, __HIP_MEMORY_SCOPE_AGENT) < epoch)
        __builtin_amdgcn_s_sleep(1);
    const char* src = (const char*)(Ag + (size_t)(r0 + row) * HH + p * 32);
    u32x4 v0, v1, v2, v3;
    asm volatile(
        "global_load_dwordx4 %0, %4, off sc0 sc1\n\t"
        "global_load_dwordx4 %1, %4, off offset:16 sc0 sc1\n\t"
        "global_load_dwordx4 %2, %4, off offset:32 sc0 sc1\n\t"
        "global_load_dwordx4 %3, %4, off offset:48 sc0 sc1\n\t"
        "s_waitcnt vmcnt(0)"
        : "=&v"(v0), "=&v"(v1), "=&v"(v2), "=&v"(v3) : "v"(src) : "memory");
    unsigned b = (unsigned)(p * 64);
    *(u32x4*)((char*)Ast + swz((unsigned)row, b))      = v0;
    *(u32x4*)((char*)Ast + swz((unsigned)row, b + 16)) = v1;
    *(u32x4*)((char*)Ast + swz((unsigned)row, b + 32)) = v2;
    *(u32x4*)((char*)Ast + swz((unsigned)row, b + 48)) = v3;
}

// ---------------- prologue kernels (proven rounds 3-13) ----------------

__global__ __launch_bounds__(256) void init_state(ushort* hp) {
    int i = blockIdx.x * 256 + threadIdx.x;
    hp[i] = 0;
}

__global__ __launch_bounds__(256) void transpose_f32_bf16(
    const float* __restrict__ in, ushort* __restrict__ out, int K, int N)
{
    __shared__ float tile[32][33];
    int tx = threadIdx.x & 31, ty = threadIdx.x >> 5;
    int bk = blockIdx.x * 32, bn = blockIdx.y * 32;
    #pragma unroll
    for (int i = 0; i < 32; i += 8)
        tile[ty + i][tx] = in[(size_t)(bk + ty + i) * N + (bn + tx)];
    __syncthreads();
    #pragma unroll
    for (int i = 0; i < 32; i += 8)
        out[(size_t)(bn + ty + i) * K + (bk + tx)] = f2bf(tile[tx][ty + i]);
}

__global__ __launch_bounds__(256) void combine_w(
    const float* __restrict__ base, const float* __restrict__ A,
    const float* __restrict__ Bm, float* __restrict__ out, int use_base)
{
    int n  = blockIdx.x * 256 + threadIdx.x;
    int k0 = blockIdx.y * 8;
    float acc[8];
    #pragma unroll
    for (int r = 0; r < 8; ++r)
        acc[r] = use_base ? base[(size_t)(k0 + r) * G4 + n] : 0.f;
    for (int m = 0; m < 512; ++m) {
        float bv = Bm[(size_t)m * G4 + n];
        #pragma unroll
        for (int r = 0; r < 8; ++r)
            acc[r] = fmaf(A[(size_t)(k0 + r) * 512 + m], bv, acc[r]);
    }
    #pragma unroll
    for (int r = 0; r < 8; ++r) out[(size_t)(k0 + r) * G4 + n] = acc[r];
}

__global__ __launch_bounds__(256) void bias_g_kernel(
    const float* __restrict__ Wih_b, const float* __restrict__ Whm_b,
    const float* __restrict__ Wmx_b, const float* __restrict__ Wmh_b,
    const float* __restrict__ Whm, float* __restrict__ bias_g)
{
    int n = blockIdx.x * 256 + threadIdx.x;
    float acc = Wih_b[n] + Whm_b[n];
    for (int m = 0; m < 512; ++m)
        acc = fmaf(Wmx_b[m] + Wmh_b[m], Whm[(size_t)m * G4 + n], acc);
    bias_g[n] = acc;
}

// ---------------- persistent fused kernel ----------------
// 256 WGs x 256 thr, 1 WG/CU (92KB LDS). WG = (rb = blockIdx>>4: 16 batch
// rows, cs = blockIdx&15: 32 cols). Compute identical to r11/r13. r14:
// per-wave arrival sub-flags + fused poll/stage (5 -> 3 syncthreads/round).

__device__ __forceinline__ void mog_compute(
    const ushort* Ast, const ushort* Wlds,
    ushort (*myBuf)[32], ushort* __restrict__ outG,
    const float* __restrict__ xscale, float (*pbuf)[16][16],
    int r0, int cs, int t, int tid)
{
    int lane = tid & 63, wave = tid >> 6;
    int lr = lane & 15, lk = lane >> 4;
    int ct = wave & 1, kh = wave >> 1;
    int colloc = ct * 16 + lr;

    float xs[4];
    if (xscale != nullptr && kh == 0) {
        #pragma unroll
        for (int r = 0; r < 4; ++r)
            xs[r] = xscale[((size_t)(r0 + lk * 4 + r) * LL + t) * HH + cs * 32 + colloc];
    }

    f32x4 acc = {0.f, 0.f, 0.f, 0.f};
    #pragma unroll
    for (int kk = 0; kk < 8; ++kk) {
        short8 a = *(const short8*)((const char*)Ast +
                     swz((unsigned)lr, (unsigned)(kh * 512 + kk * 64 + lk * 16)));
        short8 b = *(const short8*)((const char*)Wlds +
                     swz((unsigned)colloc, (unsigned)(kh * 512 + kk * 64 + lk * 16)));
        acc = __builtin_amdgcn_mfma_f32_16x16x32_bf16(a, b, acc, 0, 0, 0);
    }

    if (kh == 1) {
        #pragma unroll
        for (int r = 0; r < 4; ++r) pbuf[ct][lk * 4 + r][lr] = acc[r];
    }
    __syncthreads();
    if (kh == 0) {
        #pragma unroll
        for (int r = 0; r < 4; ++r) {
            float v = acc[r] + pbuf[ct][lk * 4 + r][lr];
            float sc = (xscale != nullptr) ? xs[r] : bf2f(myBuf[lk * 4 + r][colloc]);
            myBuf[lk * 4 + r][colloc] = f2bf(2.f * sigf(v) * sc);  // C/D: col=lane&15, row=(lane>>4)*4+r
        }
    }
    __syncthreads();
    {   // publish my 1 KB tile (coalesced u32 stores)
        int row = tid >> 4, c2 = tid & 15;
        unsigned v = *(const unsigned*)&myBuf[row][c2 * 2];
        agst32((char*)outG + (((size_t)(r0 + row)) * HH + cs * 32 + c2 * 2) * 2, v);
    }
}

__global__ __launch_bounds__(256) void moglstm_persistent(
    const float* __restrict__ x,
    const ushort* __restrict__ QT, const ushort* __restrict__ RT,
    const ushort* __restrict__ W1T, const ushort* __restrict__ W2T,
    const float* __restrict__ biasg,
    ushort* __restrict__ hp, ushort* __restrict__ xa, ushort* __restrict__ hb1,
    ushort* __restrict__ xb, ushort* __restrict__ hb2, ushort* __restrict__ xc,
    float* __restrict__ out, unsigned* __restrict__ flags)
{
    __shared__ ushort QTs[32 * 512];      // 32 KB swizzled [local col][K]
    __shared__ ushort RTs[32 * 512];      // 32 KB
    __shared__ ushort Ast[16 * 512];      // 16 KB staged A-tile (swizzled)
    __shared__ float  pbuf[2][16][16];    // 2 KB
    __shared__ ushort myX[16][32];        // 1 KB
    __shared__ ushort myH[16][32];        // 1 KB
    __shared__ float  gbuf[4][16][32];    // 8 KB   -> ~92 KB -> 1 WG/CU

    int tid = threadIdx.x;
    int rb = blockIdx.x >> 4, cs = blockIdx.x & 15;
    int r0 = rb * 16;
    int lane = tid & 63, wave = tid >> 6;
    int lr = lane & 15, lk = lane >> 4;

    // Q/R weight slices -> LDS once (plain cached loads; read-only)
    #pragma unroll
    for (int i = 0; i < 8; ++i) {
        int ch = i * 256 + tid, col = ch >> 6, kc = ch & 63;
        *(u32x4*)((char*)QTs + swz((unsigned)col, (unsigned)(kc * 16))) =
            *(const u32x4*)(QT + (size_t)(cs * 32 + col) * HH + kc * 8);
        *(u32x4*)((char*)RTs + swz((unsigned)col, (unsigned)(kc * 16))) =
            *(const u32x4*)(RT + (size_t)(cs * 32 + col) * HH + kc * 8);
    }
    ((unsigned*)myH)[tid] = 0;            // h0 = 0
    float Creg0 = 0.f, Creg1 = 0.f;       // cell state lives in VGPRs all run
    __syncthreads();

    unsigned* fl = flags + rb * 64;       // 16 cs x 4 waves sub-flags

    for (int t = 0; t < LL; ++t) {
        unsigned ep = (unsigned)t * 6u;   // epoch of stage s = ep + s

        // S1: x1 = 2*sig(h0 @ Q) * x_t    (polls prev step's S6 = ep)
        stage_poll(hp, r0, Ast, fl, ep, tid); __syncthreads();
        mog_compute(Ast, QTs, myX, xa, x, pbuf, r0, cs, t, tid);
        arrive_wave(fl, cs, ep + 1, tid);
        // S2: h1 = 2*sig(x1 @ R) * h0
        stage_poll(xa, r0, Ast, fl, ep + 1, tid); __syncthreads();
        mog_compute(Ast, RTs, myH, hb1, nullptr, pbuf, r0, cs, t, tid);
        arrive_wave(fl, cs, ep + 2, tid);
        // S3: x2 = 2*sig(h1 @ Q) * x1
        stage_poll(hb1, r0, Ast, fl, ep + 2, tid); __syncthreads();
        mog_compute(Ast, QTs, myX, xb, nullptr, pbuf, r0, cs, t, tid);
        arrive_wave(fl, cs, ep + 3, tid);
        // S4: h2 = 2*sig(x2 @ R) * h1
        stage_poll(xb, r0, Ast, fl, ep + 3, tid); __syncthreads();
        mog_compute(Ast, RTs, myH, hb2, nullptr, pbuf, r0, cs, t, tid);
        arrive_wave(fl, cs, ep + 4, tid);
        // S5: x3 = 2*sig(h2 @ Q) * x2   — Ast = h2, reused by W2 below
        stage_poll(hb2, r0, Ast, fl, ep + 4, tid); __syncthreads();
        mog_compute(Ast, QTs, myX, xc, nullptr, pbuf, r0, cs, t, tid);
        arrive_wave(fl, cs, ep + 5, tid);

        // --- S6: gates = x3@W1 + h2@W2 + bias; LSTM cell. wave = quadrant q.
        int q = wave;
        f32x4 acc0 = {0,0,0,0}, acc1 = {0,0,0,0};
        {   // W2 partial from Ast (= h2), overlaps ep+5 transport
            const short8* B0 = (const short8*)(W2T + (size_t)(q * 512 + cs * 32 + lr) * HH);
            const short8* B1 = (const short8*)(W2T + (size_t)(q * 512 + cs * 32 + 16 + lr) * HH);
            #pragma unroll
            for (int kk = 0; kk < 16; ++kk) {
                short8 a = *(const short8*)((const char*)Ast +
                             swz((unsigned)lr, (unsigned)(kk * 64 + lk * 16)));
                acc0 = __builtin_amdgcn_mfma_f32_16x16x32_bf16(a, B0[kk * 4 + lk], acc0, 0, 0, 0);
                acc1 = __builtin_amdgcn_mfma_f32_16x16x32_bf16(a, B1[kk * 4 + lk], acc1, 0, 0, 0);
            }
        }
        __syncthreads();                  // all W2 Ast-reads done before restage
        stage_poll(xc, r0, Ast, fl, ep + 5, tid); __syncthreads();
        {   // W1 with x3
            const short8* B0 = (const short8*)(W1T + (size_t)(q * 512 + cs * 32 + lr) * HH);
            const short8* B1 = (const short8*)(W1T + (size_t)(q * 512 + cs * 32 + 16 + lr) * HH);
            #pragma unroll
            for (int kk = 0; kk < 16; ++kk) {
                short8 a = *(const short8*)((const char*)Ast +
                             swz((unsigned)lr, (unsigned)(kk * 64 + lk * 16)));
                acc0 = __builtin_amdgcn_mfma_f32_16x16x32_bf16(a, B0[kk * 4 + lk], acc0, 0, 0, 0);
                acc1 = __builtin_amdgcn_mfma_f32_16x16x32_bf16(a, B1[kk * 4 + lk], acc1, 0, 0, 0);
            }
        }
        {
            float b0 = biasg[q * 512 + cs * 32 + lr];
            float b1 = biasg[q * 512 + cs * 32 + 16 + lr];
            #pragma unroll
            for (int r = 0; r < 4; ++r) {
                gbuf[q][lk * 4 + r][lr]      = acc0[r] + b0;
                gbuf[q][lk * 4 + r][16 + lr] = acc1[r] + b1;
            }
        }
        __syncthreads();
        {   // cell: thread owns (row=tid>>4, cols 2*(tid&15)+{0,1}) forever
            int row = tid >> 4, c2 = tid & 15;
            int colg = cs * 32 + c2 * 2;
            float i0 = sigf(gbuf[0][row][c2 * 2]),      f0 = sigf(gbuf[1][row][c2 * 2]);
            float g0 = tanhf(gbuf[2][row][c2 * 2]),     o0 = sigf(gbuf[3][row][c2 * 2]);
            Creg0 = f0 * Creg0 + i0 * g0;
            float h0v = o0 * tanhf(Creg0);
            float i1 = sigf(gbuf[0][row][c2 * 2 + 1]),  f1 = sigf(gbuf[1][row][c2 * 2 + 1]);
            float g1 = tanhf(gbuf[2][row][c2 * 2 + 1]), o1 = sigf(gbuf[3][row][c2 * 2 + 1]);
            Creg1 = f1 * Creg1 + i1 * g1;
            float h1v = o1 * tanhf(Creg1);
            f32x2 hv2 = {h0v, h1v};
            *(f32x2*)(out + ((size_t)(r0 + row) * LL + t) * HH + colg) = hv2;  // (B,L,H)
            unsigned hu = (unsigned)f2bf(h0v) | ((unsigned)f2bf(h1v) << 16);
            agst32((char*)hp + (((size_t)(r0 + row)) * HH + colg) * 2, hu);    // h_t for S1(t+1)
            *(unsigned*)&myH[row][c2 * 2] = hu;                                // local copy for S2
        }
        arrive_wave(fl, cs, ep + 6, tid);
    }
}

// ---------------- host launcher ----------------
extern "C" void kernel_launch(void* const* d_in, const int* in_sizes, int n_in,
                              void* d_out, int out_size, void* d_ws, size_t ws_size,
                              hipStream_t stream)
{
    const float* x     = (const float*)d_in[0];   // (256,256,512)
    const float* Wih_w = (const float*)d_in[1];   // (512,2048)
    const float* Wih_b = (const float*)d_in[2];   // (2048)
    const float* Wmx_w = (const float*)d_in[3];   // (512,512)
    const float* Wmx_b = (const float*)d_in[4];   // (512)
    const float* Wmh_w = (const float*)d_in[5];   // (512,512)
    const float* Wmh_b = (const float*)d_in[6];   // (512)
    const float* Whm_w = (const float*)d_in[7];   // (512,2048)
    const float* Whm_b = (const float*)d_in[8];   // (2048)
    const float* Q     = (const float*)d_in[9];   // (512,512)
    const float* R     = (const float*)d_in[10];  // (512,512)
    float* out = (float*)d_out;                   // (256,256,512)

    char* ws = (char*)d_ws;
    ushort* QT   = (ushort*)ws;               ws += (size_t)512 * 512 * 2;   // bf16 [outcol][K]
    ushort* RT   = (ushort*)ws;               ws += (size_t)512 * 512 * 2;
    ushort* W1T  = (ushort*)ws;               ws += (size_t)G4  * 512 * 2;
    ushort* W2T  = (ushort*)ws;               ws += (size_t)G4  * 512 * 2;
    float*  biasg= (float*)ws;                ws += (size_t)G4 * 4;
    ushort* xa   = (ushort*)ws;               ws += (size_t)BB * HH * 2;
    ushort* hb1  = (ushort*)ws;               ws += (size_t)BB * HH * 2;
    ushort* xb   = (ushort*)ws;               ws += (size_t)BB * HH * 2;
    ushort* hb2  = (ushort*)ws;               ws += (size_t)BB * HH * 2;
    ushort* xc   = (ushort*)ws;               ws += (size_t)BB * HH * 2;
    ushort* hp   = (ushort*)ws;               ws += (size_t)BB * HH * 2;
    float*  Wtmp = (float*)ws;                ws += (size_t)512 * G4 * 4;    // prologue-only

    // Sub-flags alias post-prologue-dead Wtmp: 16 rb x 16 cs x 4 waves = 4 KB.
    unsigned* flags = (unsigned*)Wtmp;

    // prologue: state init + weight prep
    init_state<<<512, 256, 0, stream>>>(hp);
    transpose_f32_bf16<<<dim3(16, 16), 256, 0, stream>>>(Q, QT, 512, 512);
    transpose_f32_bf16<<<dim3(16, 16), 256, 0, stream>>>(R, RT, 512, 512);
    combine_w<<<dim3(8, 64), 256, 0, stream>>>(Wih_w, Wmx_w, Whm_w, Wtmp, 1);   // W1 = Wih + Wmx@Whm
    transpose_f32_bf16<<<dim3(16, 64), 256, 0, stream>>>(Wtmp, W1T, 512, G4);
    combine_w<<<dim3(8, 64), 256, 0, stream>>>(nullptr, Wmh_w, Whm_w, Wtmp, 0); // W2 = Wmh@Whm
    transpose_f32_bf16<<<dim3(16, 64), 256, 0, stream>>>(Wtmp, W2T, 512, G4);
    bias_g_kernel<<<8, 256, 0, stream>>>(Wih_b, Whm_b, Wmx_b, Wmh_b, Whm_w, biasg);
    hipMemsetAsync(flags, 0, (size_t)16 * 64 * sizeof(unsigned), stream);

    // one persistent kernel for the entire sequence
    moglstm_persistent<<<256, 256, 0, stream>>>(x, QT, RT, W1T, W2T, biasg,
                                                hp, xa, hb1, xb, hb2, xc, out, flags);
}

// Round 15
// 7933.012 us; speedup vs baseline: 1.0265x; 1.0265x over previous
//
#include <hip/hip_runtime.h>
#include <hip/hip_bf16.h>
#include <cmath>

// ---------------- types & helpers ----------------
typedef __attribute__((ext_vector_type(8))) short short8;   // 8 bf16
typedef __attribute__((ext_vector_type(4))) float f32x4;
typedef __attribute__((ext_vector_type(2))) float f32x2;
typedef __attribute__((ext_vector_type(4))) unsigned int u32x4;

__device__ inline float bf2f(ushort u) {
    unsigned v = (unsigned)u << 16; float f; __builtin_memcpy(&f, &v, 4); return f;
}
__device__ inline ushort f2bf(float f) {
    __hip_bfloat16 h = __float2bfloat16(f); ushort u; __builtin_memcpy(&u, &h, 2); return u;
}
__device__ inline float sigf(float z) { return 1.f / (1.f + expf(-z)); }

// publish store (agent scope — r13-proven)
__device__ __forceinline__ void agst32(void* p, unsigned v) {
    __hip_atomic_store((unsigned*)p, v, __ATOMIC_RELAXED, __HIP_MEMORY_SCOPE_AGENT);
}

// dims
#define BB 256
#define LL 256
#define HH 512
#define G4 2048

// XOR swizzle for 1024-B LDS rows (proven r4-r14)
__device__ __forceinline__ unsigned swz(unsigned row, unsigned byteInRow) {
    return (row * 1024u + byteInRow) ^ ((row & 7u) << 4);
}

// Cooperative A-tile stage (r11/r13, proven): 16 rows x 512 cols bf16 from
// global (sc0 sc1) into swizzled LDS. 256 thr x 64 contiguous bytes.
__device__ __forceinline__ void stage_A16(const ushort* Ag, int r0, ushort* Ast, int tid) {
    const char* src = (const char*)(Ag + (size_t)(r0 + (tid >> 4)) * HH + (tid & 15) * 32);
    u32x4 v0, v1, v2, v3;
    asm volatile(
        "global_load_dwordx4 %0, %4, off sc0 sc1\n\t"
        "global_load_dwordx4 %1, %4, off offset:16 sc0 sc1\n\t"
        "global_load_dwordx4 %2, %4, off offset:32 sc0 sc1\n\t"
        "global_load_dwordx4 %3, %4, off offset:48 sc0 sc1\n\t"
        "s_waitcnt vmcnt(0)"
        : "=&v"(v0), "=&v"(v1), "=&v"(v2), "=&v"(v3) : "v"(src) : "memory");
    unsigned row = (unsigned)(tid >> 4), b = (unsigned)((tid & 15) * 64);
    *(u32x4*)((char*)Ast + swz(row, b))      = v0;
    *(u32x4*)((char*)Ast + swz(row, b + 16)) = v1;
    *(u32x4*)((char*)Ast + swz(row, b + 32)) = v2;
    *(u32x4*)((char*)Ast + swz(row, b + 48)) = v3;
}

// ---- r15 barrier: per-wave arrival (NO workgroup sync), full-WG wait ----
// Sub-flags: fl[cs*4 + wave], one 256B block per row-group.
// arrive_w: each wave drains ITS OWN publish stores (vmcnt is per-wave),
// lane0 stores its sub-flag. No __syncthreads (r13's arrive had one).
__device__ __forceinline__ void arrive_w(unsigned* fl, int cs, unsigned epoch, int tid) {
    asm volatile("s_waitcnt vmcnt(0)" ::: "memory");
    if ((tid & 63) == 0)
        __hip_atomic_store(fl + cs * 4 + (tid >> 6), epoch,
                           __ATOMIC_RELAXED, __HIP_MEMORY_SCOPE_AGENT);
}
// wait_w: threads 0..63 poll the 64 sub-flags (one each); sync.
__device__ __forceinline__ void wait_w(unsigned* fl, unsigned epoch, int tid) {
    if (tid < 64)
        while (__hip_atomic_load(fl + tid, __ATOMIC_RELAXED,
                                 __HIP_MEMORY_SCOPE_AGENT) < epoch)
            __builtin_amdgcn_s_sleep(1);
    __syncthreads();
}

// ---------------- prologue kernels (proven rounds 3-14) ----------------

__global__ __launch_bounds__(256) void init_state(ushort* hp) {
    int i = blockIdx.x * 256 + threadIdx.x;
    hp[i] = 0;
}

__global__ __launch_bounds__(256) void transpose_f32_bf16(
    const float* __restrict__ in, ushort* __restrict__ out, int K, int N)
{
    __shared__ float tile[32][33];
    int tx = threadIdx.x & 31, ty = threadIdx.x >> 5;
    int bk = blockIdx.x * 32, bn = blockIdx.y * 32;
    #pragma unroll
    for (int i = 0; i < 32; i += 8)
        tile[ty + i][tx] = in[(size_t)(bk + ty + i) * N + (bn + tx)];
    __syncthreads();
    #pragma unroll
    for (int i = 0; i < 32; i += 8)
        out[(size_t)(bn + ty + i) * K + (bk + tx)] = f2bf(tile[tx][ty + i]);
}

__global__ __launch_bounds__(256) void combine_w(
    const float* __restrict__ base, const float* __restrict__ A,
    const float* __restrict__ Bm, float* __restrict__ out, int use_base)
{
    int n  = blockIdx.x * 256 + threadIdx.x;
    int k0 = blockIdx.y * 8;
    float acc[8];
    #pragma unroll
    for (int r = 0; r < 8; ++r)
        acc[r] = use_base ? base[(size_t)(k0 + r) * G4 + n] : 0.f;
    for (int m = 0; m < 512; ++m) {
        float bv = Bm[(size_t)m * G4 + n];
        #pragma unroll
        for (int r = 0; r < 8; ++r)
            acc[r] = fmaf(A[(size_t)(k0 + r) * 512 + m], bv, acc[r]);
    }
    #pragma unroll
    for (int r = 0; r < 8; ++r) out[(size_t)(k0 + r) * G4 + n] = acc[r];
}

__global__ __launch_bounds__(256) void bias_g_kernel(
    const float* __restrict__ Wih_b, const float* __restrict__ Whm_b,
    const float* __restrict__ Wmx_b, const float* __restrict__ Wmh_b,
    const float* __restrict__ Whm, float* __restrict__ bias_g)
{
    int n = blockIdx.x * 256 + threadIdx.x;
    float acc = Wih_b[n] + Whm_b[n];
    for (int m = 0; m < 512; ++m)
        acc = fmaf(Wmx_b[m] + Wmh_b[m], Whm[(size_t)m * G4 + n], acc);
    bias_g[n] = acc;
}

// ---------------- persistent fused kernel ----------------
// 256 WGs x 256 thr, 1 WG/CU (92KB LDS). WG = (rb = blockIdx>>4: 16 batch
// rows, cs = blockIdx&15: 32 cols). Structure = r13 (best). r15 delta:
// per-wave arrival flags (drops the arrive-side __syncthreads).

__device__ __forceinline__ void mog_stage_p(
    const ushort* Ast, const ushort* Wlds,
    ushort (*myBuf)[32], ushort* __restrict__ outG,
    const float* __restrict__ xscale, float (*pbuf)[16][16],
    int r0, int cs, int t, int tid)
{
    int lane = tid & 63, wave = tid >> 6;
    int lr = lane & 15, lk = lane >> 4;
    int ct = wave & 1, kh = wave >> 1;
    int colloc = ct * 16 + lr;

    float xs[4];
    if (xscale != nullptr && kh == 0) {
        #pragma unroll
        for (int r = 0; r < 4; ++r)
            xs[r] = xscale[((size_t)(r0 + lk * 4 + r) * LL + t) * HH + cs * 32 + colloc];
    }

    f32x4 acc = {0.f, 0.f, 0.f, 0.f};
    #pragma unroll
    for (int kk = 0; kk < 8; ++kk) {
        short8 a = *(const short8*)((const char*)Ast +
                     swz((unsigned)lr, (unsigned)(kh * 512 + kk * 64 + lk * 16)));
        short8 b = *(const short8*)((const char*)Wlds +
                     swz((unsigned)colloc, (unsigned)(kh * 512 + kk * 64 + lk * 16)));
        acc = __builtin_amdgcn_mfma_f32_16x16x32_bf16(a, b, acc, 0, 0, 0);
    }

    if (kh == 1) {
        #pragma unroll
        for (int r = 0; r < 4; ++r) pbuf[ct][lk * 4 + r][lr] = acc[r];
    }
    __syncthreads();
    if (kh == 0) {
        #pragma unroll
        for (int r = 0; r < 4; ++r) {
            float v = acc[r] + pbuf[ct][lk * 4 + r][lr];
            float sc = (xscale != nullptr) ? xs[r] : bf2f(myBuf[lk * 4 + r][colloc]);
            myBuf[lk * 4 + r][colloc] = f2bf(2.f * sigf(v) * sc);  // C/D: col=lane&15, row=(lane>>4)*4+r
        }
    }
    __syncthreads();
    {   // publish my 1 KB tile (coalesced u32 agent stores)
        int row = tid >> 4, c2 = tid & 15;
        unsigned v = *(const unsigned*)&myBuf[row][c2 * 2];
        agst32((char*)outG + (((size_t)(r0 + row)) * HH + cs * 32 + c2 * 2) * 2, v);
    }
}

__global__ __launch_bounds__(256) void moglstm_persistent(
    const float* __restrict__ x,
    const ushort* __restrict__ QT, const ushort* __restrict__ RT,
    const ushort* __restrict__ W1T, const ushort* __restrict__ W2T,
    const float* __restrict__ biasg,
    ushort* __restrict__ hp, ushort* __restrict__ xa, ushort* __restrict__ hb1,
    ushort* __restrict__ xb, ushort* __restrict__ hb2, ushort* __restrict__ xc,
    float* __restrict__ out, unsigned* __restrict__ flags)
{
    __shared__ ushort QTs[32 * 512];      // 32 KB swizzled [local col][K]
    __shared__ ushort RTs[32 * 512];      // 32 KB
    __shared__ ushort Ast[16 * 512];      // 16 KB staged A-tile (swizzled)
    __shared__ float  pbuf[2][16][16];    // 2 KB
    __shared__ ushort myX[16][32];        // 1 KB
    __shared__ ushort myH[16][32];        // 1 KB
    __shared__ float  gbuf[4][16][32];    // 8 KB   -> ~92 KB -> 1 WG/CU

    int tid = threadIdx.x;
    int rb = blockIdx.x >> 4, cs = blockIdx.x & 15;
    int r0 = rb * 16;
    int lane = tid & 63, wave = tid >> 6;
    int lr = lane & 15, lk = lane >> 4;

    // Q/R weight slices -> LDS once (plain cached loads; read-only)
    #pragma unroll
    for (int i = 0; i < 8; ++i) {
        int ch = i * 256 + tid, col = ch >> 6, kc = ch & 63;
        *(u32x4*)((char*)QTs + swz((unsigned)col, (unsigned)(kc * 16))) =
            *(const u32x4*)(QT + (size_t)(cs * 32 + col) * HH + kc * 8);
        *(u32x4*)((char*)RTs + swz((unsigned)col, (unsigned)(kc * 16))) =
            *(const u32x4*)(RT + (size_t)(cs * 32 + col) * HH + kc * 8);
    }
    ((unsigned*)myH)[tid] = 0;            // h0 = 0
    float Creg0 = 0.f, Creg1 = 0.f;       // cell state lives in VGPRs all run
    __syncthreads();

    unsigned* fl = flags + rb * 64;       // 16 cs x 4 waves sub-flags (256 B)

    for (int t = 0; t < LL; ++t) {
        unsigned ep = (unsigned)t * 6u;

        // S1: x1 = 2*sig(h0 @ Q) * x_t   (hp certified by prev ep+6 barrier)
        stage_A16(hp, r0, Ast, tid); __syncthreads();
        mog_stage_p(Ast, QTs, myX, xa, x, pbuf, r0, cs, t, tid);
        arrive_w(fl, cs, ep + 1, tid); wait_w(fl, ep + 1, tid);
        // S2: h1 = 2*sig(x1 @ R) * h0
        stage_A16(xa, r0, Ast, tid); __syncthreads();
        mog_stage_p(Ast, RTs, myH, hb1, nullptr, pbuf, r0, cs, t, tid);
        arrive_w(fl, cs, ep + 2, tid); wait_w(fl, ep + 2, tid);
        // S3: x2 = 2*sig(h1 @ Q) * x1
        stage_A16(hb1, r0, Ast, tid); __syncthreads();
        mog_stage_p(Ast, QTs, myX, xb, nullptr, pbuf, r0, cs, t, tid);
        arrive_w(fl, cs, ep + 3, tid); wait_w(fl, ep + 3, tid);
        // S4: h2 = 2*sig(x2 @ R) * h1
        stage_A16(xb, r0, Ast, tid); __syncthreads();
        mog_stage_p(Ast, RTs, myH, hb2, nullptr, pbuf, r0, cs, t, tid);
        arrive_w(fl, cs, ep + 4, tid); wait_w(fl, ep + 4, tid);

        // S5: x3 = 2*sig(h2 @ Q) * x2   — A-tile (h2) staged once, shared with W2
        stage_A16(hb2, r0, Ast, tid); __syncthreads();
        mog_stage_p(Ast, QTs, myX, xc, nullptr, pbuf, r0, cs, t, tid);
        arrive_w(fl, cs, ep + 5, tid);

        // --- inside S5's wait window: gate partial h2 @ W2 (Ast still = h2) ---
        int q = wave;
        f32x4 acc0 = {0,0,0,0}, acc1 = {0,0,0,0};
        {
            const short8* B0 = (const short8*)(W2T + (size_t)(q * 512 + cs * 32 + lr) * HH);
            const short8* B1 = (const short8*)(W2T + (size_t)(q * 512 + cs * 32 + 16 + lr) * HH);
            #pragma unroll
            for (int kk = 0; kk < 16; ++kk) {
                short8 a = *(const short8*)((const char*)Ast +
                             swz((unsigned)lr, (unsigned)(kk * 64 + lk * 16)));
                acc0 = __builtin_amdgcn_mfma_f32_16x16x32_bf16(a, B0[kk * 4 + lk], acc0, 0, 0, 0);
                acc1 = __builtin_amdgcn_mfma_f32_16x16x32_bf16(a, B1[kk * 4 + lk], acc1, 0, 0, 0);
            }
        }
        wait_w(fl, ep + 5, tid);          // x3 published by all peers; also fences Ast reuse

        // S6: gates += x3 @ W1; bias; LSTM cell
        stage_A16(xc, r0, Ast, tid); __syncthreads();
        {
            const short8* B0 = (const short8*)(W1T + (size_t)(q * 512 + cs * 32 + lr) * HH);
            const short8* B1 = (const short8*)(W1T + (size_t)(q * 512 + cs * 32 + 16 + lr) * HH);
            #pragma unroll
            for (int kk = 0; kk < 16; ++kk) {
                short8 a = *(const short8*)((const char*)Ast +
                             swz((unsigned)lr, (unsigned)(kk * 64 + lk * 16)));
                acc0 = __builtin_amdgcn_mfma_f32_16x16x32_bf16(a, B0[kk * 4 + lk], acc0, 0, 0, 0);
                acc1 = __builtin_amdgcn_mfma_f32_16x16x32_bf16(a, B1[kk * 4 + lk], acc1, 0, 0, 0);
            }
        }
        {
            float b0 = biasg[q * 512 + cs * 32 + lr];
            float b1 = biasg[q * 512 + cs * 32 + 16 + lr];
            #pragma unroll
            for (int r = 0; r < 4; ++r) {
                gbuf[q][lk * 4 + r][lr]      = acc0[r] + b0;
                gbuf[q][lk * 4 + r][16 + lr] = acc1[r] + b1;
            }
        }
        __syncthreads();
        {   // cell: thread owns (row=tid>>4, cols 2*(tid&15)+{0,1}) forever
            int row = tid >> 4, c2 = tid & 15;
            int colg = cs * 32 + c2 * 2;
            float i0 = sigf(gbuf[0][row][c2 * 2]),      f0 = sigf(gbuf[1][row][c2 * 2]);
            float g0 = tanhf(gbuf[2][row][c2 * 2]),     o0 = sigf(gbuf[3][row][c2 * 2]);
            Creg0 = f0 * Creg0 + i0 * g0;
            float h0v = o0 * tanhf(Creg0);
            float i1 = sigf(gbuf[0][row][c2 * 2 + 1]),  f1 = sigf(gbuf[1][row][c2 * 2 + 1]);
            float g1 = tanhf(gbuf[2][row][c2 * 2 + 1]), o1 = sigf(gbuf[3][row][c2 * 2 + 1]);
            Creg1 = f1 * Creg1 + i1 * g1;
            float h1v = o1 * tanhf(Creg1);
            f32x2 hv2 = {h0v, h1v};
            *(f32x2*)(out + ((size_t)(r0 + row) * LL + t) * HH + colg) = hv2;  // (B,L,H)
            unsigned hu = (unsigned)f2bf(h0v) | ((unsigned)f2bf(h1v) << 16);
            agst32((char*)hp + (((size_t)(r0 + row)) * HH + colg) * 2, hu);    // h_t for S1(t+1)
            *(unsigned*)&myH[row][c2 * 2] = hu;                                // local copy for S2
        }
        arrive_w(fl, cs, ep + 6, tid); wait_w(fl, ep + 6, tid);
    }
}

// ---------------- host launcher ----------------
extern "C" void kernel_launch(void* const* d_in, const int* in_sizes, int n_in,
                              void* d_out, int out_size, void* d_ws, size_t ws_size,
                              hipStream_t stream)
{
    const float* x     = (const float*)d_in[0];   // (256,256,512)
    const float* Wih_w = (const float*)d_in[1];   // (512,2048)
    const float* Wih_b = (const float*)d_in[2];   // (2048)
    const float* Wmx_w = (const float*)d_in[3];   // (512,512)
    const float* Wmx_b = (const float*)d_in[4];   // (512)
    const float* Wmh_w = (const float*)d_in[5];   // (512,512)
    const float* Wmh_b = (const float*)d_in[6];   // (512)
    const float* Whm_w = (const float*)d_in[7];   // (512,2048)
    const float* Whm_b = (const float*)d_in[8];   // (2048)
    const float* Q     = (const float*)d_in[9];   // (512,512)
    const float* R     = (const float*)d_in[10];  // (512,512)
    float* out = (float*)d_out;                   // (256,256,512)

    char* ws = (char*)d_ws;
    ushort* QT   = (ushort*)ws;               ws += (size_t)512 * 512 * 2;   // bf16 [outcol][K]
    ushort* RT   = (ushort*)ws;               ws += (size_t)512 * 512 * 2;
    ushort* W1T  = (ushort*)ws;               ws += (size_t)G4  * 512 * 2;
    ushort* W2T  = (ushort*)ws;               ws += (size_t)G4  * 512 * 2;
    float*  biasg= (float*)ws;                ws += (size_t)G4 * 4;
    ushort* xa   = (ushort*)ws;               ws += (size_t)BB * HH * 2;
    ushort* hb1  = (ushort*)ws;               ws += (size_t)BB * HH * 2;
    ushort* xb   = (ushort*)ws;               ws += (size_t)BB * HH * 2;
    ushort* hb2  = (ushort*)ws;               ws += (size_t)BB * HH * 2;
    ushort* xc   = (ushort*)ws;               ws += (size_t)BB * HH * 2;
    ushort* hp   = (ushort*)ws;               ws += (size_t)BB * HH * 2;
    float*  Wtmp = (float*)ws;                ws += (size_t)512 * G4 * 4;    // prologue-only

    // Sub-flags alias post-prologue-dead Wtmp: 16 rb x 64 = 4 KB.
    unsigned* flags = (unsigned*)Wtmp;

    // prologue: state init + weight prep
    init_state<<<512, 256, 0, stream>>>(hp);
    transpose_f32_bf16<<<dim3(16, 16), 256, 0, stream>>>(Q, QT, 512, 512);
    transpose_f32_bf16<<<dim3(16, 16), 256, 0, stream>>>(R, RT, 512, 512);
    combine_w<<<dim3(8, 64), 256, 0, stream>>>(Wih_w, Wmx_w, Whm_w, Wtmp, 1);   // W1 = Wih + Wmx@Whm
    transpose_f32_bf16<<<dim3(16, 64), 256, 0, stream>>>(Wtmp, W1T, 512, G4);
    combine_w<<<dim3(8, 64), 256, 0, stream>>>(nullptr, Wmh_w, Whm_w, Wtmp, 0); // W2 = Wmh@Whm
    transpose_f32_bf16<<<dim3(16, 64), 256, 0, stream>>>(Wtmp, W2T, 512, G4);
    bias_g_kernel<<<8, 256, 0, stream>>>(Wih_b, Whm_b, Wmx_b, Wmh_b, Whm_w, biasg);
    hipMemsetAsync(flags, 0, (size_t)16 * 64 * sizeof(unsigned), stream);

    // one persistent kernel for the entire sequence
    moglstm_persistent<<<256, 256, 0, stream>>>(x, QT, RT, W1T, W2T, biasg,
                                                hp, xa, hb1, xb, hb2, xc, out, flags);
}

// Round 16
// 7274.458 us; speedup vs baseline: 1.1195x; 1.0905x over previous
//
#include <hip/hip_runtime.h>
#include <hip/hip_bf16.h>
#include <cmath>

// ---------------- types & helpers ----------------
typedef __attribute__((ext_vector_type(8))) short short8;   // 8 bf16
typedef __attribute__((ext_vector_type(4))) float f32x4;
typedef __attribute__((ext_vector_type(2))) float f32x2;
typedef __attribute__((ext_vector_type(4))) unsigned int u32x4;

__device__ inline float bf2f(ushort u) {
    unsigned v = (unsigned)u << 16; float f; __builtin_memcpy(&f, &v, 4); return f;
}
__device__ inline ushort f2bf(float f) {
    __hip_bfloat16 h = __float2bfloat16(f); ushort u; __builtin_memcpy(&u, &h, 2); return u;
}
__device__ inline float sigf(float z) { return 1.f / (1.f + expf(-z)); }

// AGENT-scope publish (r13 — best measured configuration)
__device__ __forceinline__ void agst32(void* p, unsigned v) {
    __hip_atomic_store((unsigned*)p, v, __ATOMIC_RELAXED, __HIP_MEMORY_SCOPE_AGENT);
}

// dims
#define BB 256
#define LL 256
#define HH 512
#define G4 2048

// XOR swizzle for 1024-B LDS rows (proven r4-r15)
__device__ __forceinline__ unsigned swz(unsigned row, unsigned byteInRow) {
    return (row * 1024u + byteInRow) ^ ((row & 7u) << 4);
}

// Cooperative A-tile stage (r11, proven): 16 rows x 512 cols bf16 from global
// (device-coherent load: sc0 sc1) into swizzled LDS. 256 thr x 64 contiguous
// bytes: fully coalesced.
__device__ __forceinline__ void stage_A16(const ushort* Ag, int r0, ushort* Ast, int tid) {
    const char* src = (const char*)(Ag + (size_t)(r0 + (tid >> 4)) * HH + (tid & 15) * 32);
    u32x4 v0, v1, v2, v3;
    asm volatile(
        "global_load_dwordx4 %0, %4, off sc0 sc1\n\t"
        "global_load_dwordx4 %1, %4, off offset:16 sc0 sc1\n\t"
        "global_load_dwordx4 %2, %4, off offset:32 sc0 sc1\n\t"
        "global_load_dwordx4 %3, %4, off offset:48 sc0 sc1\n\t"
        "s_waitcnt vmcnt(0)"
        : "=&v"(v0), "=&v"(v1), "=&v"(v2), "=&v"(v3) : "v"(src) : "memory");
    unsigned row = (unsigned)(tid >> 4), b = (unsigned)((tid & 15) * 64);
    *(u32x4*)((char*)Ast + swz(row, b))      = v0;
    *(u32x4*)((char*)Ast + swz(row, b + 16)) = v1;
    *(u32x4*)((char*)Ast + swz(row, b + 32)) = v2;
    *(u32x4*)((char*)Ast + swz(row, b + 48)) = v3;
}

// Epoch-slot barrier, split arrive/wait (r11/r13, proven best).
__device__ __forceinline__ void rb_arrive(unsigned* slots, int sub, unsigned epoch) {
    asm volatile("s_waitcnt vmcnt(0)" ::: "memory");   // my publish stores done
    __syncthreads();                                   // all waves done
    if (threadIdx.x == 0)
        __hip_atomic_store(slots + sub, epoch, __ATOMIC_RELAXED, __HIP_MEMORY_SCOPE_AGENT);
}
__device__ __forceinline__ void rb_wait(unsigned* slots, unsigned epoch) {
    if (threadIdx.x < 16)
        while (__hip_atomic_load(slots + threadIdx.x, __ATOMIC_RELAXED,
                                 __HIP_MEMORY_SCOPE_AGENT) < epoch)
            __builtin_amdgcn_s_sleep(1);
    __syncthreads();
}

// ---------------- prologue kernels (proven rounds 3-15) ----------------

__global__ __launch_bounds__(256) void init_state(ushort* hp) {
    int i = blockIdx.x * 256 + threadIdx.x;
    hp[i] = 0;
}

__global__ __launch_bounds__(256) void transpose_f32_bf16(
    const float* __restrict__ in, ushort* __restrict__ out, int K, int N)
{
    __shared__ float tile[32][33];
    int tx = threadIdx.x & 31, ty = threadIdx.x >> 5;
    int bk = blockIdx.x * 32, bn = blockIdx.y * 32;
    #pragma unroll
    for (int i = 0; i < 32; i += 8)
        tile[ty + i][tx] = in[(size_t)(bk + ty + i) * N + (bn + tx)];
    __syncthreads();
    #pragma unroll
    for (int i = 0; i < 32; i += 8)
        out[(size_t)(bn + ty + i) * K + (bk + tx)] = f2bf(tile[tx][ty + i]);
}

__global__ __launch_bounds__(256) void combine_w(
    const float* __restrict__ base, const float* __restrict__ A,
    const float* __restrict__ Bm, float* __restrict__ out, int use_base)
{
    int n  = blockIdx.x * 256 + threadIdx.x;
    int k0 = blockIdx.y * 8;
    float acc[8];
    #pragma unroll
    for (int r = 0; r < 8; ++r)
        acc[r] = use_base ? base[(size_t)(k0 + r) * G4 + n] : 0.f;
    for (int m = 0; m < 512; ++m) {
        float bv = Bm[(size_t)m * G4 + n];
        #pragma unroll
        for (int r = 0; r < 8; ++r)
            acc[r] = fmaf(A[(size_t)(k0 + r) * 512 + m], bv, acc[r]);
    }
    #pragma unroll
    for (int r = 0; r < 8; ++r) out[(size_t)(k0 + r) * G4 + n] = acc[r];
}

__global__ __launch_bounds__(256) void bias_g_kernel(
    const float* __restrict__ Wih_b, const float* __restrict__ Whm_b,
    const float* __restrict__ Wmx_b, const float* __restrict__ Wmh_b,
    const float* __restrict__ Whm, float* __restrict__ bias_g)
{
    int n = blockIdx.x * 256 + threadIdx.x;
    float acc = Wih_b[n] + Whm_b[n];
    for (int m = 0; m < 512; ++m)
        acc = fmaf(Wmx_b[m] + Wmh_b[m], Whm[(size_t)m * G4 + n], acc);
    bias_g[n] = acc;
}

// ---------------- persistent fused kernel (r13 — final best) ----------------
// 256 WGs x 256 thr, 1 WG/CU (92KB LDS). WG = (rb = blockIdx>>4: 16 batch
// rows, cs = blockIdx&15: 32 cols). Wall = 1536 serial cross-WG rounds x
// ~4.7us transport floor (measured across 8 sync/transport variants).

__device__ __forceinline__ void mog_stage_p(
    const ushort* Ast,            // staged A-tile (16 x 512 bf16, swizzled)
    const ushort* Wlds,
    ushort (*myBuf)[32], ushort* __restrict__ outG,
    const float* __restrict__ xscale, float (*pbuf)[16][16],
    int r0, int cs, int t, int tid)
{
    int lane = tid & 63, wave = tid >> 6;
    int lr = lane & 15, lk = lane >> 4;
    int ct = wave & 1, kh = wave >> 1;
    int colloc = ct * 16 + lr;

    float xs[4];
    if (xscale != nullptr && kh == 0) {
        #pragma unroll
        for (int r = 0; r < 4; ++r)
            xs[r] = xscale[((size_t)(r0 + lk * 4 + r) * LL + t) * HH + cs * 32 + colloc];
    }

    f32x4 acc = {0.f, 0.f, 0.f, 0.f};
    #pragma unroll
    for (int kk = 0; kk < 8; ++kk) {
        short8 a = *(const short8*)((const char*)Ast +
                     swz((unsigned)lr, (unsigned)(kh * 512 + kk * 64 + lk * 16)));
        short8 b = *(const short8*)((const char*)Wlds +
                     swz((unsigned)colloc, (unsigned)(kh * 512 + kk * 64 + lk * 16)));
        acc = __builtin_amdgcn_mfma_f32_16x16x32_bf16(a, b, acc, 0, 0, 0);
    }

    if (kh == 1) {
        #pragma unroll
        for (int r = 0; r < 4; ++r) pbuf[ct][lk * 4 + r][lr] = acc[r];
    }
    __syncthreads();
    if (kh == 0) {
        #pragma unroll
        for (int r = 0; r < 4; ++r) {
            float v = acc[r] + pbuf[ct][lk * 4 + r][lr];
            float sc = (xscale != nullptr) ? xs[r] : bf2f(myBuf[lk * 4 + r][colloc]);
            myBuf[lk * 4 + r][colloc] = f2bf(2.f * sigf(v) * sc);  // C/D: col=lane&15, row=(lane>>4)*4+r
        }
    }
    __syncthreads();
    {   // publish my 1 KB tile (coalesced u32 AGENT stores)
        int row = tid >> 4, c2 = tid & 15;
        unsigned v = *(const unsigned*)&myBuf[row][c2 * 2];
        agst32((char*)outG + (((size_t)(r0 + row)) * HH + cs * 32 + c2 * 2) * 2, v);
    }
}

__global__ __launch_bounds__(256) void moglstm_persistent(
    const float* __restrict__ x,
    const ushort* __restrict__ QT, const ushort* __restrict__ RT,
    const ushort* __restrict__ W1T, const ushort* __restrict__ W2T,
    const float* __restrict__ biasg,
    ushort* __restrict__ hp, ushort* __restrict__ xa, ushort* __restrict__ hb1,
    ushort* __restrict__ xb, ushort* __restrict__ hb2, ushort* __restrict__ xc,
    float* __restrict__ out, unsigned* __restrict__ flags)
{
    __shared__ ushort QTs[32 * 512];      // 32 KB swizzled [local col][K]
    __shared__ ushort RTs[32 * 512];      // 32 KB
    __shared__ ushort Ast[16 * 512];      // 16 KB staged A-tile (swizzled)
    __shared__ float  pbuf[2][16][16];    // 2 KB
    __shared__ ushort myX[16][32];        // 1 KB
    __shared__ ushort myH[16][32];        // 1 KB
    __shared__ float  gbuf[4][16][32];    // 8 KB   -> ~92 KB -> 1 WG/CU

    int tid = threadIdx.x;
    int rb = blockIdx.x >> 4, cs = blockIdx.x & 15;
    int r0 = rb * 16;
    int lane = tid & 63, wave = tid >> 6;
    int lr = lane & 15, lk = lane >> 4;

    // Q/R weight slices -> LDS once (plain cached loads; read-only)
    #pragma unroll
    for (int i = 0; i < 8; ++i) {
        int ch = i * 256 + tid, col = ch >> 6, kc = ch & 63;
        *(u32x4*)((char*)QTs + swz((unsigned)col, (unsigned)(kc * 16))) =
            *(const u32x4*)(QT + (size_t)(cs * 32 + col) * HH + kc * 8);
        *(u32x4*)((char*)RTs + swz((unsigned)col, (unsigned)(kc * 16))) =
            *(const u32x4*)(RT + (size_t)(cs * 32 + col) * HH + kc * 8);
    }
    ((unsigned*)myH)[tid] = 0;            // h0 = 0
    float Creg0 = 0.f, Creg1 = 0.f;       // cell state lives in VGPRs all run
    __syncthreads();

    unsigned* slots = flags + rb * 16;    // 16 u32 per row-group

    for (int t = 0; t < LL; ++t) {
        unsigned ep = (unsigned)t * 6u;

        // S1: x1 = 2*sig(h0 @ Q) * x_t
        stage_A16(hp, r0, Ast, tid); __syncthreads();
        mog_stage_p(Ast, QTs, myX, xa, x, pbuf, r0, cs, t, tid);
        rb_arrive(slots, cs, ep + 1); rb_wait(slots, ep + 1);
        // S2: h1 = 2*sig(x1 @ R) * h0
        stage_A16(xa, r0, Ast, tid); __syncthreads();
        mog_stage_p(Ast, RTs, myH, hb1, nullptr, pbuf, r0, cs, t, tid);
        rb_arrive(slots, cs, ep + 2); rb_wait(slots, ep + 2);
        // S3: x2 = 2*sig(h1 @ Q) * x1
        stage_A16(hb1, r0, Ast, tid); __syncthreads();
        mog_stage_p(Ast, QTs, myX, xb, nullptr, pbuf, r0, cs, t, tid);
        rb_arrive(slots, cs, ep + 3); rb_wait(slots, ep + 3);
        // S4: h2 = 2*sig(x2 @ R) * h1
        stage_A16(xb, r0, Ast, tid); __syncthreads();
        mog_stage_p(Ast, RTs, myH, hb2, nullptr, pbuf, r0, cs, t, tid);
        rb_arrive(slots, cs, ep + 4); rb_wait(slots, ep + 4);

        // S5: x3 = 2*sig(h2 @ Q) * x2   — A-tile (h2) staged once, shared with W2
        stage_A16(hb2, r0, Ast, tid); __syncthreads();
        mog_stage_p(Ast, QTs, myX, xc, nullptr, pbuf, r0, cs, t, tid);
        rb_arrive(slots, cs, ep + 5);

        // --- inside S5's wait window: gate partial h2 @ W2 (Ast still = h2) ---
        int q = wave;
        f32x4 acc0 = {0,0,0,0}, acc1 = {0,0,0,0};
        {
            const short8* B0 = (const short8*)(W2T + (size_t)(q * 512 + cs * 32 + lr) * HH);
            const short8* B1 = (const short8*)(W2T + (size_t)(q * 512 + cs * 32 + 16 + lr) * HH);
            #pragma unroll
            for (int kk = 0; kk < 16; ++kk) {
                short8 a = *(const short8*)((const char*)Ast +
                             swz((unsigned)lr, (unsigned)(kk * 64 + lk * 16)));
                acc0 = __builtin_amdgcn_mfma_f32_16x16x32_bf16(a, B0[kk * 4 + lk], acc0, 0, 0, 0);
                acc1 = __builtin_amdgcn_mfma_f32_16x16x32_bf16(a, B1[kk * 4 + lk], acc1, 0, 0, 0);
            }
        }
        rb_wait(slots, ep + 5);           // x3 now published by all peers

        // S6: gates += x3 @ W1; bias; LSTM cell
        stage_A16(xc, r0, Ast, tid); __syncthreads();
        {
            const short8* B0 = (const short8*)(W1T + (size_t)(q * 512 + cs * 32 + lr) * HH);
            const short8* B1 = (const short8*)(W1T + (size_t)(q * 512 + cs * 32 + 16 + lr) * HH);
            #pragma unroll
            for (int kk = 0; kk < 16; ++kk) {
                short8 a = *(const short8*)((const char*)Ast +
                             swz((unsigned)lr, (unsigned)(kk * 64 + lk * 16)));
                acc0 = __builtin_amdgcn_mfma_f32_16x16x32_bf16(a, B0[kk * 4 + lk], acc0, 0, 0, 0);
                acc1 = __builtin_amdgcn_mfma_f32_16x16x32_bf16(a, B1[kk * 4 + lk], acc1, 0, 0, 0);
            }
        }
        {
            float b0 = biasg[q * 512 + cs * 32 + lr];
            float b1 = biasg[q * 512 + cs * 32 + 16 + lr];
            #pragma unroll
            for (int r = 0; r < 4; ++r) {
                gbuf[q][lk * 4 + r][lr]      = acc0[r] + b0;
                gbuf[q][lk * 4 + r][16 + lr] = acc1[r] + b1;
            }
        }
        __syncthreads();
        {   // cell: thread owns (row=tid>>4, cols 2*(tid&15)+{0,1}) forever
            int row = tid >> 4, c2 = tid & 15;
            int colg = cs * 32 + c2 * 2;
            float i0 = sigf(gbuf[0][row][c2 * 2]),      f0 = sigf(gbuf[1][row][c2 * 2]);
            float g0 = tanhf(gbuf[2][row][c2 * 2]),     o0 = sigf(gbuf[3][row][c2 * 2]);
            Creg0 = f0 * Creg0 + i0 * g0;
            float h0v = o0 * tanhf(Creg0);
            float i1 = sigf(gbuf[0][row][c2 * 2 + 1]),  f1 = sigf(gbuf[1][row][c2 * 2 + 1]);
            float g1 = tanhf(gbuf[2][row][c2 * 2 + 1]), o1 = sigf(gbuf[3][row][c2 * 2 + 1]);
            Creg1 = f1 * Creg1 + i1 * g1;
            float h1v = o1 * tanhf(Creg1);
            f32x2 hv2 = {h0v, h1v};
            *(f32x2*)(out + ((size_t)(r0 + row) * LL + t) * HH + colg) = hv2;  // (B,L,H)
            unsigned hu = (unsigned)f2bf(h0v) | ((unsigned)f2bf(h1v) << 16);
            agst32((char*)hp + (((size_t)(r0 + row)) * HH + colg) * 2, hu);    // h_t for S1(t+1)
            *(unsigned*)&myH[row][c2 * 2] = hu;                                // local copy for S2
        }
        rb_arrive(slots, cs, ep + 6); rb_wait(slots, ep + 6);
    }
}

// ---------------- host launcher ----------------
extern "C" void kernel_launch(void* const* d_in, const int* in_sizes, int n_in,
                              void* d_out, int out_size, void* d_ws, size_t ws_size,
                              hipStream_t stream)
{
    const float* x     = (const float*)d_in[0];   // (256,256,512)
    const float* Wih_w = (const float*)d_in[1];   // (512,2048)
    const float* Wih_b = (const float*)d_in[2];   // (2048)
    const float* Wmx_w = (const float*)d_in[3];   // (512,512)
    const float* Wmx_b = (const float*)d_in[4];   // (512)
    const float* Wmh_w = (const float*)d_in[5];   // (512,512)
    const float* Wmh_b = (const float*)d_in[6];   // (512)
    const float* Whm_w = (const float*)d_in[7];   // (512,2048)
    const float* Whm_b = (const float*)d_in[8];   // (2048)
    const float* Q     = (const float*)d_in[9];   // (512,512)
    const float* R     = (const float*)d_in[10];  // (512,512)
    float* out = (float*)d_out;                   // (256,256,512)

    char* ws = (char*)d_ws;
    ushort* QT   = (ushort*)ws;               ws += (size_t)512 * 512 * 2;   // bf16 [outcol][K]
    ushort* RT   = (ushort*)ws;               ws += (size_t)512 * 512 * 2;
    ushort* W1T  = (ushort*)ws;               ws += (size_t)G4  * 512 * 2;
    ushort* W2T  = (ushort*)ws;               ws += (size_t)G4  * 512 * 2;
    float*  biasg= (float*)ws;                ws += (size_t)G4 * 4;
    ushort* xa   = (ushort*)ws;               ws += (size_t)BB * HH * 2;
    ushort* hb1  = (ushort*)ws;               ws += (size_t)BB * HH * 2;
    ushort* xb   = (ushort*)ws;               ws += (size_t)BB * HH * 2;
    ushort* hb2  = (ushort*)ws;               ws += (size_t)BB * HH * 2;
    ushort* xc   = (ushort*)ws;               ws += (size_t)BB * HH * 2;
    ushort* hp   = (ushort*)ws;               ws += (size_t)BB * HH * 2;
    float*  Wtmp = (float*)ws;                ws += (size_t)512 * G4 * 4;    // prologue-only

    // Epoch slots alias post-prologue-dead Wtmp: 16 rb x 16 slots u32 = 1 KB.
    unsigned* flags = (unsigned*)Wtmp;

    // prologue: state init + weight prep
    init_state<<<512, 256, 0, stream>>>(hp);
    transpose_f32_bf16<<<dim3(16, 16), 256, 0, stream>>>(Q, QT, 512, 512);
    transpose_f32_bf16<<<dim3(16, 16), 256, 0, stream>>>(R, RT, 512, 512);
    combine_w<<<dim3(8, 64), 256, 0, stream>>>(Wih_w, Wmx_w, Whm_w, Wtmp, 1);   // W1 = Wih + Wmx@Whm
    transpose_f32_bf16<<<dim3(16, 64), 256, 0, stream>>>(Wtmp, W1T, 512, G4);
    combine_w<<<dim3(8, 64), 256, 0, stream>>>(nullptr, Wmh_w, Whm_w, Wtmp, 0); // W2 = Wmh@Whm
    transpose_f32_bf16<<<dim3(16, 64), 256, 0, stream>>>(Wtmp, W2T, 512, G4);
    bias_g_kernel<<<8, 256, 0, stream>>>(Wih_b, Whm_b, Wmx_b, Wmh_b, Whm_w, biasg);
    hipMemsetAsync(flags, 0, (size_t)16 * 16 * sizeof(unsigned), stream);

    // one persistent kernel for the entire sequence
    moglstm_persistent<<<256, 256, 0, stream>>>(x, QT, RT, W1T, W2T, biasg,
                                                hp, xa, hb1, xb, hb2, xc, out, flags);
}